// Round 1
// 1302.153 us; speedup vs baseline: 1.2002x; 1.2002x over previous
//
#include <hip/hip_runtime.h>
#include <hip/hip_bf16.h>
#include <cstdint>

// Problem constants
#define BB 2
#define SS 2048
#define DD 2048
#define HH 16
#define HD 128
#define FF 8192
#define QKVD 6144  // 3*DD

typedef __bf16 bf16x8 __attribute__((ext_vector_type(8)));
typedef float floatx4 __attribute__((ext_vector_type(4)));

#define LOG2E 1.4426950408889634f

__device__ __forceinline__ unsigned short f2bf(float f) {
  unsigned u = __builtin_bit_cast(unsigned, f);
  u += 0x7FFFu + ((u >> 16) & 1u);
  return (unsigned short)(u >> 16);
}
__device__ __forceinline__ float bf2f(unsigned short h) {
  return __builtin_bit_cast(float, (unsigned)h << 16);
}

__device__ __forceinline__ void load_lds_16B(const void* g, void* l) {
  __builtin_amdgcn_global_load_lds(
      (const __attribute__((address_space(1))) unsigned int*)g,
      (__attribute__((address_space(3))) unsigned int*)l, 16, 0, 0);
}

// ---------------- fp32 -> bf16 convert ----------------
__global__ void f32_to_bf16_vec(const float* __restrict__ src,
                                unsigned short* __restrict__ dst, int n4) {
  int i = blockIdx.x * 256 + threadIdx.x;
  if (i < n4) {
    float4 v = ((const float4*)src)[i];
    ushort4 o;
    o.x = f2bf(v.x); o.y = f2bf(v.y); o.z = f2bf(v.z); o.w = f2bf(v.w);
    ((ushort4*)dst)[i] = o;
  }
}

// ---------------- RMSNorm (fp32 in, bf16 out) ----------------
__global__ __launch_bounds__(256) void rmsnorm_bf16(const float* __restrict__ x,
                                                    const float* __restrict__ w,
                                                    unsigned short* __restrict__ xn) {
  const int row = blockIdx.x, tid = threadIdx.x;
  const float4* xr = (const float4*)(x + (size_t)row * DD);
  float4 a = xr[tid], b = xr[tid + 256];
  float ss = a.x * a.x + a.y * a.y + a.z * a.z + a.w * a.w +
             b.x * b.x + b.y * b.y + b.z * b.z + b.w * b.w;
#pragma unroll
  for (int off = 1; off < 64; off <<= 1) ss += __shfl_xor(ss, off);
  __shared__ float red[4];
  if ((tid & 63) == 0) red[tid >> 6] = ss;
  __syncthreads();
  float tot = red[0] + red[1] + red[2] + red[3];
  float sc = rsqrtf(tot * (1.0f / (float)DD) + 1e-5f);
  const float4* wr = (const float4*)w;
  float4 wa = wr[tid], wb = wr[tid + 256];
  ushort4 oa, ob;
  oa.x = f2bf(a.x * sc * wa.x); oa.y = f2bf(a.y * sc * wa.y);
  oa.z = f2bf(a.z * sc * wa.z); oa.w = f2bf(a.w * sc * wa.w);
  ob.x = f2bf(b.x * sc * wb.x); ob.y = f2bf(b.y * sc * wb.y);
  ob.z = f2bf(b.z * sc * wb.z); ob.w = f2bf(b.w * sc * wb.w);
  *(ushort4*)&xn[(size_t)row * DD + tid * 4] = oa;
  *(ushort4*)&xn[(size_t)row * DD + (tid + 256) * 4] = ob;
}

// ---------------- GEMM: C[M,N] = A[M,K] @ Bw[N,K]^T  (bf16 in, fp32 acc) ----
// 256x256 tile, BK=64, 8 waves (2M x 4N), 8-phase schedule with counted vmcnt.
// LDS: A/B each [2 dbuf][2 half][128 x 64] bf16 = 128 KiB total.
//   A half h holds m-quadrant-h rows of both M-wave groups: row (wm*64+rq) maps
//   to global tile row wm*128 + h*64 + rq.  (read only in phases with mq==h)
//   B half h holds n-quadrant-h cols of all 4 N-wave groups: row (wn*32+cq)
//   maps to global tile col wn*64 + h*32 + cq.  (read only in phases nq==h)
// Chunk swizzle: 16B chunk c of LDS row r holds global chunk c^(r&7); applied
// on the global source (linear LDS dest for global_load_lds) and on ds_read.
// MODE 0: store bf16
// MODE 1: store bf16 of (acc + bias[col])
// MODE 2: store bf16 of (aux[idx] + relu(acc + bias[col]))   (aux may == Cout)
// MODE 3: store fp32 of (acc + bias[col] + res[idx])
template <int MODE>
__global__ __launch_bounds__(512, 1) void gemm_bt(
    const unsigned short* __restrict__ A, const unsigned short* __restrict__ Bw,
    void* __restrict__ Cout, const float* __restrict__ bias,
    const unsigned short* __restrict__ aux, const float* __restrict__ res,
    int M, int N, int K) {
  __shared__ __align__(16) unsigned short As[2][2][128 * 64];
  __shared__ __align__(16) unsigned short Bs[2][2][128 * 64];
  const int tid = threadIdx.x;
  const int lane = tid & 63, w = tid >> 6;
  const int l16 = lane & 15, quad = lane >> 4;
  const int wm = w >> 2, wn = w & 3;

  // bijective XCD-aware block swizzle (all our grids are multiples of 8)
  const int gx = gridDim.x;
  const int nwg = gx * gridDim.y;
  const int bid = blockIdx.y * gx + blockIdx.x;
  const int cpx = nwg >> 3;
  const int swzb = (bid & 7) * cpx + (bid >> 3);
  const int n0 = (swzb % gx) * 256, m0 = (swzb / gx) * 256;

  const int NT = K >> 6, NIT = NT >> 1;

  // staging source pointers (pre-swizzled chunk: sc ^ sr)
  const int sr = lane >> 3, sc = lane & 7;
  const unsigned short* pA0 = A + (size_t)(m0 + w * 8 + sr) * K + (sc ^ sr) * 8;
  const unsigned short* pA1 = pA0 + (size_t)128 * K;
  const unsigned short* pB0 =
      Bw + (size_t)(n0 + (w >> 2) * 64 + (w & 3) * 8 + sr) * K + (sc ^ sr) * 8;
  const unsigned short* pB1 = pB0 + (size_t)128 * K;

#define STAGE_A(d, h, kt)                                              \
  {                                                                    \
    const int _k = ((kt) < NT ? (kt) : NT - 1) * 64;                   \
    const size_t _ho = (size_t)(h) * 64 * K;                           \
    load_lds_16B(pA0 + _ho + _k, &As[d][h][(w * 8) * 64]);             \
    load_lds_16B(pA1 + _ho + _k, &As[d][h][(64 + w * 8) * 64]);        \
  }
#define STAGE_B(d, h, kt)                                              \
  {                                                                    \
    const int _k = ((kt) < NT ? (kt) : NT - 1) * 64;                   \
    const size_t _ho = (size_t)(h) * 32 * K;                           \
    load_lds_16B(pB0 + _ho + _k, &Bs[d][h][(w * 8) * 64]);             \
    load_lds_16B(pB1 + _ho + _k, &Bs[d][h][(64 + w * 8) * 64]);        \
  }

  floatx4 acc[2][2][4][2];
#pragma unroll
  for (int a0 = 0; a0 < 2; a0++)
#pragma unroll
    for (int a1 = 0; a1 < 2; a1++)
#pragma unroll
      for (int a2 = 0; a2 < 4; a2++)
#pragma unroll
        for (int a3 = 0; a3 < 2; a3++) acc[a0][a1][a2][a3] = floatx4{0.f, 0.f, 0.f, 0.f};
  bf16x8 bb[2][2];

  // one phase: ds-read A subtile (+B if quadrant-column start), issue stages,
  // barrier, lgkm wait, MFMA burst under setprio, optional counted vmcnt wait,
  // barrier.
#define PHASE(d, mq, nq, LOADB, STAGES, VMW)                                    \
  {                                                                             \
    bf16x8 a_[4][2];                                                            \
    _Pragma("unroll") for (int fr = 0; fr < 4; ++fr) {                          \
      const int lr_ = wm * 64 + fr * 16 + l16;                                  \
      _Pragma("unroll") for (int kc = 0; kc < 2; ++kc)                          \
        a_[fr][kc] = *(const bf16x8*)&As[d][mq]                                 \
            [lr_ * 64 + (((kc * 4 + quad) ^ (l16 & 7)) * 8)];                   \
    }                                                                           \
    if (LOADB) {                                                                \
      _Pragma("unroll") for (int fn = 0; fn < 2; ++fn) {                        \
        const int lr_ = wn * 32 + fn * 16 + l16;                                \
        _Pragma("unroll") for (int kc = 0; kc < 2; ++kc)                        \
          bb[fn][kc] = *(const bf16x8*)&Bs[d][nq]                               \
              [lr_ * 64 + (((kc * 4 + quad) ^ (l16 & 7)) * 8)];                 \
      }                                                                         \
    }                                                                           \
    STAGES                                                                      \
    __builtin_amdgcn_s_barrier();                                               \
    asm volatile("s_waitcnt lgkmcnt(0)" ::: "memory");                          \
    __builtin_amdgcn_sched_barrier(0);                                          \
    __builtin_amdgcn_s_setprio(1);                                              \
    _Pragma("unroll") for (int kc = 0; kc < 2; ++kc)                            \
      _Pragma("unroll") for (int fr = 0; fr < 4; ++fr)                          \
        _Pragma("unroll") for (int fn = 0; fn < 2; ++fn)                        \
          acc[mq][nq][fr][fn] = __builtin_amdgcn_mfma_f32_16x16x32_bf16(        \
              a_[fr][kc], bb[fn][kc], acc[mq][nq][fr][fn], 0, 0, 0);            \
    __builtin_amdgcn_s_setprio(0);                                              \
    if (VMW) asm volatile("s_waitcnt vmcnt(4)" ::: "memory");                   \
    __builtin_amdgcn_s_barrier();                                               \
    asm volatile("" ::: "memory");                                              \
  }

  // prologue: tile0 -> buf0 (all 4 halves), tile1 -> buf1 (B0, A0).
  // FIFO: vmcnt(4) confirms tile0's 8 loads, leaves tile1's 4 in flight.
  STAGE_A(0, 0, 0)
  STAGE_A(0, 1, 0)
  STAGE_B(0, 0, 0)
  STAGE_B(0, 1, 0)
  STAGE_B(1, 0, 1)
  STAGE_A(1, 0, 1)
  asm volatile("s_waitcnt vmcnt(4)" ::: "memory");
  __builtin_amdgcn_s_barrier();
  asm volatile("" ::: "memory");

  // Steady state per iteration (phases 1..8; reads: buf0 tile 2it at 1-4,
  // buf1 tile 2it+1 at 5-8):
  //  p1: stage A1/b1,B1/b1 of tile 2it+1   (read p6..p8; confirmed at p4 wait)
  //  p3: stage B0/b0 of 2it+2   p4: stage A0/b0 of 2it+2, vmcnt(4)
  //  p5: stage A1/b0,B1/b0 of 2it+2        (confirmed at p8 wait)
  //  p7: stage B0/b1 of 2it+3   p8: stage A0/b1 of 2it+3, vmcnt(4)
#pragma unroll 1
  for (int it = 0; it < NIT; ++it) {
    const int t1 = 2 * it + 1, tn0 = 2 * it + 2, tn1 = 2 * it + 3;
    PHASE(0, 0, 0, true,  STAGE_A(1, 1, t1) STAGE_B(1, 1, t1), false)
    PHASE(0, 1, 0, false, , false)
    PHASE(0, 0, 1, true,  STAGE_B(0, 0, tn0), false)
    PHASE(0, 1, 1, false, STAGE_A(0, 0, tn0), true)
    PHASE(1, 0, 0, true,  STAGE_A(0, 1, tn0) STAGE_B(0, 1, tn0), false)
    PHASE(1, 1, 0, false, , false)
    PHASE(1, 0, 1, true,  STAGE_B(1, 0, tn1), false)
    PHASE(1, 1, 1, false, STAGE_A(1, 0, tn1), true)
  }
  asm volatile("s_waitcnt vmcnt(0)" ::: "memory");
#undef PHASE
#undef STAGE_A
#undef STAGE_B

  // epilogue
#pragma unroll
  for (int nq = 0; nq < 2; ++nq)
#pragma unroll
    for (int fn = 0; fn < 2; ++fn) {
      const int col = n0 + wn * 64 + nq * 32 + fn * 16 + l16;
      float bv = 0.0f;
      if constexpr (MODE >= 1) bv = bias[col];
#pragma unroll
      for (int mq = 0; mq < 2; ++mq)
#pragma unroll
        for (int fr = 0; fr < 4; ++fr) {
          const int row0 = m0 + wm * 128 + mq * 64 + fr * 16 + quad * 4;
#pragma unroll
          for (int r = 0; r < 4; ++r) {
            const size_t idx = (size_t)(row0 + r) * N + col;
            float v = acc[mq][nq][fr][fn][r];
            if constexpr (MODE == 0) {
              ((unsigned short*)Cout)[idx] = f2bf(v);
            } else if constexpr (MODE == 1) {
              ((unsigned short*)Cout)[idx] = f2bf(v + bv);
            } else if constexpr (MODE == 2) {
              float t = fmaxf(v + bv, 0.0f) + bf2f(aux[idx]);
              ((unsigned short*)Cout)[idx] = f2bf(t);
            } else {
              ((float*)Cout)[idx] = v + bv + res[idx];
            }
          }
        }
    }
}

// ---------------- Flash causal attention v3 ----------------
// Static balanced schedule: grid (8, H, B). Block p handles q-tiles {15-p, p}
// (each q-tile = 128 rows, 32 rows/wave). Work per pair = (2(15-p)+2)+(2p+2)=34
// KV tile-iters of 64 — identical for every block, no atomics.
// qkv: [B*S, 6144] bf16 rows (q|k|v per head). out: [B][H][S][HD] bf16.
__global__ __launch_bounds__(256) void attn_fwd(const unsigned short* __restrict__ qkv,
                                                unsigned short* __restrict__ out) {
  __shared__ __align__(16) unsigned short Ks[64 * 136];
  __shared__ __align__(16) unsigned short Vt[128 * 72];
  __shared__ __align__(16) unsigned short Ps[4][32 * 72];
  const int tid = threadIdx.x;
  const int lane = tid & 63, wave = tid >> 6;
  const int l16 = lane & 15, quad = lane >> 4;
  const int p = blockIdx.x, h = blockIdx.y, b = blockIdx.z;
  const float scale = 0.088388347648318447f;  // 1/sqrt(128)

#pragma unroll 1
  for (int pass = 0; pass < 2; pass++) {
    const int qt = pass == 0 ? 15 - p : p;  // heavy tile first
    const int q0w = qt * 128 + wave * 32;
    const int ntiles = 2 * qt + 2;

    // Q fragments: 32 rows x 128 cols, held for the whole pass
    bf16x8 aq[2][4];
#pragma unroll
    for (int mi = 0; mi < 2; mi++) {
      const unsigned short* Qp =
          qkv + (size_t)(b * SS + q0w + mi * 16 + l16) * QKVD + h * HD + quad * 8;
#pragma unroll
      for (int kc = 0; kc < 4; kc++) aq[mi][kc] = *(const bf16x8*)(Qp + kc * 32);
    }

    floatx4 o[2][8];
    float m_r[2][4], l_r[2][4];
#pragma unroll
    for (int mi = 0; mi < 2; mi++) {
#pragma unroll
      for (int nb = 0; nb < 8; nb++) o[mi][nb] = floatx4{0.f, 0.f, 0.f, 0.f};
#pragma unroll
      for (int r = 0; r < 4; r++) { m_r[mi][r] = -1e30f; l_r[mi][r] = 0.f; }
    }

#pragma unroll 1
    for (int t = 0; t < ntiles; t++) {
      const int kv0 = t * 64;
      const bool need_mask = (t >= ntiles - 2);
      __syncthreads();  // also protects LDS reuse across t / pass
      {
        const int cc = tid & 15;
#pragma unroll
        for (int i = 0; i < 4; i++) {
          const int r = (tid >> 4) + 16 * i;
          const size_t rowb = (size_t)(b * SS + kv0 + r) * QKVD + h * HD + cc * 8;
          *(uint4*)&Ks[r * 136 + cc * 8] = *(const uint4*)(qkv + rowb + DD);
          unsigned short tmp[8];
          *(uint4*)tmp = *(const uint4*)(qkv + rowb + 2 * DD);
          // V^T with chunk-rotation swizzle: Vt[d][kv] at chunk ((kv>>3)+(d>>3))&7
#pragma unroll
          for (int j2 = 0; j2 < 8; j2++) {
            const int d = cc * 8 + j2;
            Vt[d * 72 + (((r >> 3) + (d >> 3)) & 7) * 8 + (r & 7)] = tmp[j2];
          }
        }
      }
      __syncthreads();

      // S = Q K^T  (32q x 64kv)
      floatx4 s[2][4];
#pragma unroll
      for (int mi = 0; mi < 2; mi++)
#pragma unroll
        for (int ni = 0; ni < 4; ni++) s[mi][ni] = floatx4{0.f, 0.f, 0.f, 0.f};
#pragma unroll
      for (int kc = 0; kc < 4; kc++) {
        bf16x8 bk[4];
#pragma unroll
        for (int ni = 0; ni < 4; ni++)
          bk[ni] = *(const bf16x8*)&Ks[(ni * 16 + l16) * 136 + kc * 32 + quad * 8];
#pragma unroll
        for (int mi = 0; mi < 2; mi++)
#pragma unroll
          for (int ni = 0; ni < 4; ni++)
            s[mi][ni] = __builtin_amdgcn_mfma_f32_16x16x32_bf16(aq[mi][kc], bk[ni],
                                                                s[mi][ni], 0, 0, 0);
      }

      // online softmax
#pragma unroll
      for (int mi = 0; mi < 2; mi++) {
        float alpha[4];
#pragma unroll
        for (int r = 0; r < 4; r++) {
          const int qrow = q0w + mi * 16 + quad * 4 + r;
          float v[4];
#pragma unroll
          for (int ni = 0; ni < 4; ni++) {
            v[ni] = s[mi][ni][r] * scale;
            if (need_mask && (kv0 + ni * 16 + l16 > qrow)) v[ni] = -1e30f;
          }
          float mx = fmaxf(fmaxf(v[0], v[1]), fmaxf(v[2], v[3]));
          mx = fmaxf(mx, __shfl_xor(mx, 1));
          mx = fmaxf(mx, __shfl_xor(mx, 2));
          mx = fmaxf(mx, __shfl_xor(mx, 4));
          mx = fmaxf(mx, __shfl_xor(mx, 8));
          const float mnew = fmaxf(m_r[mi][r], mx);
          alpha[r] = exp2f((m_r[mi][r] - mnew) * LOG2E);
          m_r[mi][r] = mnew;
          float rs = 0.f;
#pragma unroll
          for (int ni = 0; ni < 4; ni++) {
            v[ni] = exp2f((v[ni] - mnew) * LOG2E);
            rs += v[ni];
          }
          rs += __shfl_xor(rs, 1);
          rs += __shfl_xor(rs, 2);
          rs += __shfl_xor(rs, 4);
          rs += __shfl_xor(rs, 8);
          l_r[mi][r] = l_r[mi][r] * alpha[r] + rs;
          unsigned short* Pw = &Ps[wave][(mi * 16 + quad * 4 + r) * 72 + l16];
#pragma unroll
          for (int ni = 0; ni < 4; ni++) Pw[ni * 16] = f2bf(v[ni]);
        }
#pragma unroll
        for (int nb = 0; nb < 8; nb++)
#pragma unroll
          for (int r = 0; r < 4; r++) o[mi][nb][r] *= alpha[r];
      }
      asm volatile("s_waitcnt lgkmcnt(0)" ::: "memory");  // Ps is wave-private

      // O += P V
      bf16x8 pa[2][2];
#pragma unroll
      for (int mi = 0; mi < 2; mi++)
#pragma unroll
        for (int kc2 = 0; kc2 < 2; kc2++)
          pa[mi][kc2] =
              *(const bf16x8*)&Ps[wave][(mi * 16 + l16) * 72 + kc2 * 32 + quad * 8];
#pragma unroll
      for (int nb = 0; nb < 8; nb++) {
        const int d = nb * 16 + l16;
#pragma unroll
        for (int kc2 = 0; kc2 < 2; kc2++) {
          const int chunk = kc2 * 4 + quad;
          bf16x8 bv = *(const bf16x8*)&Vt[d * 72 + ((chunk + (d >> 3)) & 7) * 8];
#pragma unroll
          for (int mi = 0; mi < 2; mi++)
            o[mi][nb] = __builtin_amdgcn_mfma_f32_16x16x32_bf16(pa[mi][kc2], bv,
                                                                o[mi][nb], 0, 0, 0);
        }
      }
    }

    // epilogue: out[b][h][row][d] = o / l
#pragma unroll
    for (int mi = 0; mi < 2; mi++) {
      unsigned short* Op =
          out + (size_t)((b * HH + h) * SS + q0w + mi * 16 + quad * 4) * HD + l16;
#pragma unroll
      for (int nb = 0; nb < 8; nb++)
#pragma unroll
        for (int r = 0; r < 4; r++)
          Op[(size_t)r * HD + nb * 16] = f2bf(o[mi][nb][r] / l_r[mi][r]);
    }
  }
}

// ---------------- launch ----------------
extern "C" void kernel_launch(void* const* d_in, const int* in_sizes, int n_in,
                              void* d_out, int out_size, void* d_ws, size_t ws_size,
                              hipStream_t stream) {
  const float* x = (const float*)d_in[0];
  const float* rms_w = (const float*)d_in[1];
  const float* w_qkv = (const float*)d_in[2];
  const float* w_out = (const float*)d_in[3];
  const float* w1 = (const float*)d_in[4];
  const float* b1 = (const float*)d_in[5];
  const float* w3 = (const float*)d_in[6];
  const float* b3 = (const float*)d_in[7];
  const float* w2 = (const float*)d_in[8];
  const float* b2 = (const float*)d_in[9];
  float* out = (float*)d_out;

  char* ws = (char*)d_ws;
  size_t off = 0;
  auto alloc = [&](size_t bytes) {
    char* p = ws + off;
    off += (bytes + 255) & ~(size_t)255;
    return p;
  };
  const int M = BB * SS;  // 4096
  unsigned short* wqkv_b = (unsigned short*)alloc((size_t)QKVD * DD * 2);
  unsigned short* wout_b = (unsigned short*)alloc((size_t)DD * DD * 2);
  unsigned short* w1_b = (unsigned short*)alloc((size_t)FF * DD * 2);
  unsigned short* w3_b = (unsigned short*)alloc((size_t)FF * DD * 2);
  unsigned short* w2_b = (unsigned short*)alloc((size_t)DD * FF * 2);
  unsigned short* xn_b = (unsigned short*)alloc((size_t)M * DD * 2);
  unsigned short* qkv_b = (unsigned short*)alloc((size_t)M * QKVD * 2);
  unsigned short* attn_b = (unsigned short*)alloc((size_t)M * DD * 2);
  unsigned short* h_b = (unsigned short*)alloc((size_t)M * DD * 2);
  unsigned short* act_b = (unsigned short*)alloc((size_t)M * FF * 2);

  // weight converts
  f32_to_bf16_vec<<<(QKVD * DD / 4) / 256, 256, 0, stream>>>(w_qkv, wqkv_b, QKVD * DD / 4);
  f32_to_bf16_vec<<<(DD * DD / 4) / 256, 256, 0, stream>>>(w_out, wout_b, DD * DD / 4);
  f32_to_bf16_vec<<<(FF * DD / 4) / 256, 256, 0, stream>>>(w1, w1_b, FF * DD / 4);
  f32_to_bf16_vec<<<(FF * DD / 4) / 256, 256, 0, stream>>>(w3, w3_b, FF * DD / 4);
  f32_to_bf16_vec<<<(DD * FF / 4) / 256, 256, 0, stream>>>(w2, w2_b, DD * FF / 4);

  // rmsnorm
  rmsnorm_bf16<<<M, 256, 0, stream>>>(x, rms_w, xn_b);

  // qkv = xn @ w_qkv^T   (24x16 = 384 blocks)
  gemm_bt<0><<<dim3(QKVD / 256, M / 256), 512, 0, stream>>>(
      xn_b, wqkv_b, qkv_b, nullptr, nullptr, nullptr, M, QKVD, DD);

  // attention (static balanced schedule, 256 blocks)
  attn_fwd<<<dim3(8, HH, BB), 256, 0, stream>>>(qkv_b, attn_b);

  // h = attn @ w_out^T   (8x16 = 128 blocks)
  gemm_bt<0><<<dim3(DD / 256, M / 256), 512, 0, stream>>>(
      attn_b, wout_b, h_b, nullptr, nullptr, nullptr, M, DD, DD);

  // act = h @ w1^T + b1   (32x16 = 512 blocks)
  gemm_bt<1><<<dim3(FF / 256, M / 256), 512, 0, stream>>>(
      h_b, w1_b, act_b, b1, nullptr, nullptr, M, FF, DD);

  // act = act + relu(h @ w3^T + b3)   (in-place aux read)
  gemm_bt<2><<<dim3(FF / 256, M / 256), 512, 0, stream>>>(
      h_b, w3_b, act_b, b3, act_b, nullptr, M, FF, DD);

  // out = act @ w2^T + b2 + x   (8x16 = 128 blocks, K=8192)
  gemm_bt<3><<<dim3(DD / 256, M / 256), 512, 0, stream>>>(
      act_b, w2_b, out, b2, nullptr, x, M, DD, FF);
}

// Round 2
// 1189.415 us; speedup vs baseline: 1.3140x; 1.0948x over previous
//
#include <hip/hip_runtime.h>
#include <hip/hip_bf16.h>
#include <cstdint>

// Problem constants
#define BB 2
#define SS 2048
#define DD 2048
#define HH 16
#define HD 128
#define FF 8192
#define QKVD 6144  // 3*DD

typedef __bf16 bf16x8 __attribute__((ext_vector_type(8)));
typedef float floatx4 __attribute__((ext_vector_type(4)));

#define LOG2E 1.4426950408889634f

__device__ __forceinline__ unsigned short f2bf(float f) {
  unsigned u = __builtin_bit_cast(unsigned, f);
  u += 0x7FFFu + ((u >> 16) & 1u);
  return (unsigned short)(u >> 16);
}
__device__ __forceinline__ float bf2f(unsigned short h) {
  return __builtin_bit_cast(float, (unsigned)h << 16);
}

__device__ __forceinline__ void load_lds_16B(const void* g, void* l) {
  __builtin_amdgcn_global_load_lds(
      (const __attribute__((address_space(1))) unsigned int*)g,
      (__attribute__((address_space(3))) unsigned int*)l, 16, 0, 0);
}

// ---------------- fp32 -> bf16 convert ----------------
__global__ void f32_to_bf16_vec(const float* __restrict__ src,
                                unsigned short* __restrict__ dst, int n4) {
  int i = blockIdx.x * 256 + threadIdx.x;
  if (i < n4) {
    float4 v = ((const float4*)src)[i];
    ushort4 o;
    o.x = f2bf(v.x); o.y = f2bf(v.y); o.z = f2bf(v.z); o.w = f2bf(v.w);
    ((ushort4*)dst)[i] = o;
  }
}

// ---------------- RMSNorm (fp32 in, bf16 out) ----------------
__global__ __launch_bounds__(256) void rmsnorm_bf16(const float* __restrict__ x,
                                                    const float* __restrict__ w,
                                                    unsigned short* __restrict__ xn) {
  const int row = blockIdx.x, tid = threadIdx.x;
  const float4* xr = (const float4*)(x + (size_t)row * DD);
  float4 a = xr[tid], b = xr[tid + 256];
  float ss = a.x * a.x + a.y * a.y + a.z * a.z + a.w * a.w +
             b.x * b.x + b.y * b.y + b.z * b.z + b.w * b.w;
#pragma unroll
  for (int off = 1; off < 64; off <<= 1) ss += __shfl_xor(ss, off);
  __shared__ float red[4];
  if ((tid & 63) == 0) red[tid >> 6] = ss;
  __syncthreads();
  float tot = red[0] + red[1] + red[2] + red[3];
  float sc = rsqrtf(tot * (1.0f / (float)DD) + 1e-5f);
  const float4* wr = (const float4*)w;
  float4 wa = wr[tid], wb = wr[tid + 256];
  ushort4 oa, ob;
  oa.x = f2bf(a.x * sc * wa.x); oa.y = f2bf(a.y * sc * wa.y);
  oa.z = f2bf(a.z * sc * wa.z); oa.w = f2bf(a.w * sc * wa.w);
  ob.x = f2bf(b.x * sc * wb.x); ob.y = f2bf(b.y * sc * wb.y);
  ob.z = f2bf(b.z * sc * wb.z); ob.w = f2bf(b.w * sc * wb.w);
  *(ushort4*)&xn[(size_t)row * DD + tid * 4] = oa;
  *(ushort4*)&xn[(size_t)row * DD + (tid + 256) * 4] = ob;
}

// ---------------- split-K reduce kernels ----------------
// h_b = bf16(p0 + p1)
__global__ __launch_bounds__(256) void reduce_wout(const float* __restrict__ p,
                                                   unsigned short* __restrict__ outb,
                                                   int n4) {
  int i = blockIdx.x * 256 + threadIdx.x;
  if (i < n4) {
    float4 a = ((const float4*)p)[i];
    float4 b = ((const float4*)(p + (size_t)BB * SS * DD))[i];
    ushort4 o;
    o.x = f2bf(a.x + b.x); o.y = f2bf(a.y + b.y);
    o.z = f2bf(a.z + b.z); o.w = f2bf(a.w + b.w);
    ((ushort4*)outb)[i] = o;
  }
}

// out = p0 + p1 + b2[col] + x   (fp32)
__global__ __launch_bounds__(256) void reduce_w2(const float* __restrict__ p,
                                                 const float* __restrict__ b2,
                                                 const float* __restrict__ x,
                                                 float* __restrict__ out, int n4) {
  int i = blockIdx.x * 256 + threadIdx.x;
  if (i < n4) {
    float4 a = ((const float4*)p)[i];
    float4 b = ((const float4*)(p + (size_t)BB * SS * DD))[i];
    float4 xx = ((const float4*)x)[i];
    float4 bb = ((const float4*)b2)[i & (DD / 4 - 1)];
    float4 o;
    o.x = a.x + b.x + bb.x + xx.x;
    o.y = a.y + b.y + bb.y + xx.y;
    o.z = a.z + b.z + bb.z + xx.z;
    o.w = a.w + b.w + bb.w + xx.w;
    ((float4*)out)[i] = o;
  }
}

// ---------------- GEMM: C[M,N] = A[M,K] @ Bw[N,K]^T  (bf16 in, fp32 acc) ----
// 256x256 tile, BK=64, 8 waves (2M x 4N), 8-phase schedule with counted vmcnt.
// LDS: A/B each [2 dbuf][2 half][128 x 64] bf16 = 128 KiB total.
// K here is the PER-BLOCK iteration extent; lda is the storage row stride of
// A and Bw. Split-K: gridDim.z slices, slice z starts at column z*K and (for
// MODE 4) writes its fp32 partial at offset z*M*N.
// Chunk swizzle: 16B chunk c of LDS row r holds global chunk c^(r&7); applied
// on the global source (linear LDS dest for global_load_lds) and on ds_read.
// MODE 0: store bf16
// MODE 1: store bf16 of (acc + bias[col])
// MODE 2: store bf16 of (aux[idx] + relu(acc + bias[col]))   (aux may == Cout)
// MODE 3: store fp32 of (acc + bias[col] + res[idx])
// MODE 4: store fp32 raw acc to partial buffer (split-K)
template <int MODE>
__global__ __launch_bounds__(512, 1) void gemm_bt(
    const unsigned short* __restrict__ A, const unsigned short* __restrict__ Bw,
    void* __restrict__ Cout, const float* __restrict__ bias,
    const unsigned short* __restrict__ aux, const float* __restrict__ res,
    int M, int N, int K, int lda) {
  __shared__ __align__(16) unsigned short As[2][2][128 * 64];
  __shared__ __align__(16) unsigned short Bs[2][2][128 * 64];
  const int tid = threadIdx.x;
  const int lane = tid & 63, w = tid >> 6;
  const int l16 = lane & 15, quad = lane >> 4;
  const int wm = w >> 2, wn = w & 3;

  // bijective XCD-aware block swizzle over (x,y); z is the split-K slice
  const int gx = gridDim.x;
  const int nwg = gx * gridDim.y;
  const int bid = blockIdx.y * gx + blockIdx.x;
  const int cpx = nwg >> 3;
  const int swzb = (bid & 7) * cpx + (bid >> 3);
  const int n0 = (swzb % gx) * 256, m0 = (swzb / gx) * 256;
  const size_t koff = (size_t)blockIdx.z * K;

  const int NT = K >> 6, NIT = NT >> 1;

  // staging source pointers (pre-swizzled chunk: sc ^ sr)
  const int sr = lane >> 3, sc = lane & 7;
  const unsigned short* pA0 =
      A + (size_t)(m0 + w * 8 + sr) * lda + koff + (sc ^ sr) * 8;
  const unsigned short* pA1 = pA0 + (size_t)128 * lda;
  const unsigned short* pB0 =
      Bw + (size_t)(n0 + (w >> 2) * 64 + (w & 3) * 8 + sr) * lda + koff + (sc ^ sr) * 8;
  const unsigned short* pB1 = pB0 + (size_t)128 * lda;

#define STAGE_A(d, h, kt)                                              \
  {                                                                    \
    const int _k = ((kt) < NT ? (kt) : NT - 1) * 64;                   \
    const size_t _ho = (size_t)(h) * 64 * lda;                         \
    load_lds_16B(pA0 + _ho + _k, &As[d][h][(w * 8) * 64]);             \
    load_lds_16B(pA1 + _ho + _k, &As[d][h][(64 + w * 8) * 64]);        \
  }
#define STAGE_B(d, h, kt)                                              \
  {                                                                    \
    const int _k = ((kt) < NT ? (kt) : NT - 1) * 64;                   \
    const size_t _ho = (size_t)(h) * 32 * lda;                         \
    load_lds_16B(pB0 + _ho + _k, &Bs[d][h][(w * 8) * 64]);             \
    load_lds_16B(pB1 + _ho + _k, &Bs[d][h][(64 + w * 8) * 64]);        \
  }

  floatx4 acc[2][2][4][2];
#pragma unroll
  for (int a0 = 0; a0 < 2; a0++)
#pragma unroll
    for (int a1 = 0; a1 < 2; a1++)
#pragma unroll
      for (int a2 = 0; a2 < 4; a2++)
#pragma unroll
        for (int a3 = 0; a3 < 2; a3++) acc[a0][a1][a2][a3] = floatx4{0.f, 0.f, 0.f, 0.f};
  bf16x8 bb[2][2];

  // one phase: ds-read A subtile (+B if quadrant-column start), issue stages,
  // barrier, lgkm wait, MFMA burst under setprio, optional counted vmcnt wait,
  // barrier.
#define PHASE(d, mq, nq, LOADB, STAGES, VMW)                                    \
  {                                                                             \
    bf16x8 a_[4][2];                                                            \
    _Pragma("unroll") for (int fr = 0; fr < 4; ++fr) {                          \
      const int lr_ = wm * 64 + fr * 16 + l16;                                  \
      _Pragma("unroll") for (int kc = 0; kc < 2; ++kc)                          \
        a_[fr][kc] = *(const bf16x8*)&As[d][mq]                                 \
            [lr_ * 64 + (((kc * 4 + quad) ^ (l16 & 7)) * 8)];                   \
    }                                                                           \
    if (LOADB) {                                                                \
      _Pragma("unroll") for (int fn = 0; fn < 2; ++fn) {                        \
        const int lr_ = wn * 32 + fn * 16 + l16;                                \
        _Pragma("unroll") for (int kc = 0; kc < 2; ++kc)                        \
          bb[fn][kc] = *(const bf16x8*)&Bs[d][nq]                               \
              [lr_ * 64 + (((kc * 4 + quad) ^ (l16 & 7)) * 8)];                 \
      }                                                                         \
    }                                                                           \
    STAGES                                                                      \
    __builtin_amdgcn_s_barrier();                                               \
    asm volatile("s_waitcnt lgkmcnt(0)" ::: "memory");                          \
    __builtin_amdgcn_sched_barrier(0);                                          \
    __builtin_amdgcn_s_setprio(1);                                              \
    _Pragma("unroll") for (int kc = 0; kc < 2; ++kc)                            \
      _Pragma("unroll") for (int fr = 0; fr < 4; ++fr)                          \
        _Pragma("unroll") for (int fn = 0; fn < 2; ++fn)                        \
          acc[mq][nq][fr][fn] = __builtin_amdgcn_mfma_f32_16x16x32_bf16(        \
              a_[fr][kc], bb[fn][kc], acc[mq][nq][fr][fn], 0, 0, 0);            \
    __builtin_amdgcn_s_setprio(0);                                              \
    if (VMW) asm volatile("s_waitcnt vmcnt(4)" ::: "memory");                   \
    __builtin_amdgcn_s_barrier();                                               \
    asm volatile("" ::: "memory");                                              \
  }

  // prologue: tile0 -> buf0 (all 4 halves), tile1 -> buf1 (B0, A0).
  // FIFO: vmcnt(4) confirms tile0's 8 loads, leaves tile1's 4 in flight.
  STAGE_A(0, 0, 0)
  STAGE_A(0, 1, 0)
  STAGE_B(0, 0, 0)
  STAGE_B(0, 1, 0)
  STAGE_B(1, 0, 1)
  STAGE_A(1, 0, 1)
  asm volatile("s_waitcnt vmcnt(4)" ::: "memory");
  __builtin_amdgcn_s_barrier();
  asm volatile("" ::: "memory");

  // Steady state per iteration (phases 1..8; reads: buf0 tile 2it at 1-4,
  // buf1 tile 2it+1 at 5-8):
  //  p1: stage A1/b1,B1/b1 of tile 2it+1   (read p6..p8; confirmed at p4 wait)
  //  p3: stage B0/b0 of 2it+2   p4: stage A0/b0 of 2it+2, vmcnt(4)
  //  p5: stage A1/b0,B1/b0 of 2it+2        (confirmed at p8 wait)
  //  p7: stage B0/b1 of 2it+3   p8: stage A0/b1 of 2it+3, vmcnt(4)
#pragma unroll 1
  for (int it = 0; it < NIT; ++it) {
    const int t1 = 2 * it + 1, tn0 = 2 * it + 2, tn1 = 2 * it + 3;
    PHASE(0, 0, 0, true,  STAGE_A(1, 1, t1) STAGE_B(1, 1, t1), false)
    PHASE(0, 1, 0, false, , false)
    PHASE(0, 0, 1, true,  STAGE_B(0, 0, tn0), false)
    PHASE(0, 1, 1, false, STAGE_A(0, 0, tn0), true)
    PHASE(1, 0, 0, true,  STAGE_A(0, 1, tn0) STAGE_B(0, 1, tn0), false)
    PHASE(1, 1, 0, false, , false)
    PHASE(1, 0, 1, true,  STAGE_B(1, 0, tn1), false)
    PHASE(1, 1, 1, false, STAGE_A(1, 0, tn1), true)
  }
  asm volatile("s_waitcnt vmcnt(0)" ::: "memory");
#undef PHASE
#undef STAGE_A
#undef STAGE_B

  // epilogue
#pragma unroll
  for (int nq = 0; nq < 2; ++nq)
#pragma unroll
    for (int fn = 0; fn < 2; ++fn) {
      const int col = n0 + wn * 64 + nq * 32 + fn * 16 + l16;
      float bv = 0.0f;
      if constexpr (MODE >= 1 && MODE <= 3) bv = bias[col];
#pragma unroll
      for (int mq = 0; mq < 2; ++mq)
#pragma unroll
        for (int fr = 0; fr < 4; ++fr) {
          const int row0 = m0 + wm * 128 + mq * 64 + fr * 16 + quad * 4;
#pragma unroll
          for (int r = 0; r < 4; ++r) {
            const size_t idx = (size_t)(row0 + r) * N + col;
            float v = acc[mq][nq][fr][fn][r];
            if constexpr (MODE == 0) {
              ((unsigned short*)Cout)[idx] = f2bf(v);
            } else if constexpr (MODE == 1) {
              ((unsigned short*)Cout)[idx] = f2bf(v + bv);
            } else if constexpr (MODE == 2) {
              float t = fmaxf(v + bv, 0.0f) + bf2f(aux[idx]);
              ((unsigned short*)Cout)[idx] = f2bf(t);
            } else if constexpr (MODE == 3) {
              ((float*)Cout)[idx] = v + bv + res[idx];
            } else {
              ((float*)Cout)[(size_t)blockIdx.z * ((size_t)M * N) + idx] = v;
            }
          }
        }
    }
}

// ---------------- Flash causal attention v3 ----------------
// Static balanced schedule: grid (8, H, B). Block p handles q-tiles {15-p, p}
// (each q-tile = 128 rows, 32 rows/wave). Work per pair = (2(15-p)+2)+(2p+2)=34
// KV tile-iters of 64 — identical for every block, no atomics.
// qkv: [B*S, 6144] bf16 rows (q|k|v per head). out: [B][H][S][HD] bf16.
__global__ __launch_bounds__(256) void attn_fwd(const unsigned short* __restrict__ qkv,
                                                unsigned short* __restrict__ out) {
  __shared__ __align__(16) unsigned short Ks[64 * 136];
  __shared__ __align__(16) unsigned short Vt[128 * 72];
  __shared__ __align__(16) unsigned short Ps[4][32 * 72];
  const int tid = threadIdx.x;
  const int lane = tid & 63, wave = tid >> 6;
  const int l16 = lane & 15, quad = lane >> 4;
  const int p = blockIdx.x, h = blockIdx.y, b = blockIdx.z;
  const float scale = 0.088388347648318447f;  // 1/sqrt(128)

#pragma unroll 1
  for (int pass = 0; pass < 2; pass++) {
    const int qt = pass == 0 ? 15 - p : p;  // heavy tile first
    const int q0w = qt * 128 + wave * 32;
    const int ntiles = 2 * qt + 2;

    // Q fragments: 32 rows x 128 cols, held for the whole pass
    bf16x8 aq[2][4];
#pragma unroll
    for (int mi = 0; mi < 2; mi++) {
      const unsigned short* Qp =
          qkv + (size_t)(b * SS + q0w + mi * 16 + l16) * QKVD + h * HD + quad * 8;
#pragma unroll
      for (int kc = 0; kc < 4; kc++) aq[mi][kc] = *(const bf16x8*)(Qp + kc * 32);
    }

    floatx4 o[2][8];
    float m_r[2][4], l_r[2][4];
#pragma unroll
    for (int mi = 0; mi < 2; mi++) {
#pragma unroll
      for (int nb = 0; nb < 8; nb++) o[mi][nb] = floatx4{0.f, 0.f, 0.f, 0.f};
#pragma unroll
      for (int r = 0; r < 4; r++) { m_r[mi][r] = -1e30f; l_r[mi][r] = 0.f; }
    }

#pragma unroll 1
    for (int t = 0; t < ntiles; t++) {
      const int kv0 = t * 64;
      const bool need_mask = (t >= ntiles - 2);
      __syncthreads();  // also protects LDS reuse across t / pass
      {
        const int cc = tid & 15;
#pragma unroll
        for (int i = 0; i < 4; i++) {
          const int r = (tid >> 4) + 16 * i;
          const size_t rowb = (size_t)(b * SS + kv0 + r) * QKVD + h * HD + cc * 8;
          *(uint4*)&Ks[r * 136 + cc * 8] = *(const uint4*)(qkv + rowb + DD);
          unsigned short tmp[8];
          *(uint4*)tmp = *(const uint4*)(qkv + rowb + 2 * DD);
          // V^T with chunk-rotation swizzle: Vt[d][kv] at chunk ((kv>>3)+(d>>3))&7
#pragma unroll
          for (int j2 = 0; j2 < 8; j2++) {
            const int d = cc * 8 + j2;
            Vt[d * 72 + (((r >> 3) + (d >> 3)) & 7) * 8 + (r & 7)] = tmp[j2];
          }
        }
      }
      __syncthreads();

      // S = Q K^T  (32q x 64kv)
      floatx4 s[2][4];
#pragma unroll
      for (int mi = 0; mi < 2; mi++)
#pragma unroll
        for (int ni = 0; ni < 4; ni++) s[mi][ni] = floatx4{0.f, 0.f, 0.f, 0.f};
#pragma unroll
      for (int kc = 0; kc < 4; kc++) {
        bf16x8 bk[4];
#pragma unroll
        for (int ni = 0; ni < 4; ni++)
          bk[ni] = *(const bf16x8*)&Ks[(ni * 16 + l16) * 136 + kc * 32 + quad * 8];
#pragma unroll
        for (int mi = 0; mi < 2; mi++)
#pragma unroll
          for (int ni = 0; ni < 4; ni++)
            s[mi][ni] = __builtin_amdgcn_mfma_f32_16x16x32_bf16(aq[mi][kc], bk[ni],
                                                                s[mi][ni], 0, 0, 0);
      }

      // online softmax
#pragma unroll
      for (int mi = 0; mi < 2; mi++) {
        float alpha[4];
#pragma unroll
        for (int r = 0; r < 4; r++) {
          const int qrow = q0w + mi * 16 + quad * 4 + r;
          float v[4];
#pragma unroll
          for (int ni = 0; ni < 4; ni++) {
            v[ni] = s[mi][ni][r] * scale;
            if (need_mask && (kv0 + ni * 16 + l16 > qrow)) v[ni] = -1e30f;
          }
          float mx = fmaxf(fmaxf(v[0], v[1]), fmaxf(v[2], v[3]));
          mx = fmaxf(mx, __shfl_xor(mx, 1));
          mx = fmaxf(mx, __shfl_xor(mx, 2));
          mx = fmaxf(mx, __shfl_xor(mx, 4));
          mx = fmaxf(mx, __shfl_xor(mx, 8));
          const float mnew = fmaxf(m_r[mi][r], mx);
          alpha[r] = exp2f((m_r[mi][r] - mnew) * LOG2E);
          m_r[mi][r] = mnew;
          float rs = 0.f;
#pragma unroll
          for (int ni = 0; ni < 4; ni++) {
            v[ni] = exp2f((v[ni] - mnew) * LOG2E);
            rs += v[ni];
          }
          rs += __shfl_xor(rs, 1);
          rs += __shfl_xor(rs, 2);
          rs += __shfl_xor(rs, 4);
          rs += __shfl_xor(rs, 8);
          l_r[mi][r] = l_r[mi][r] * alpha[r] + rs;
          unsigned short* Pw = &Ps[wave][(mi * 16 + quad * 4 + r) * 72 + l16];
#pragma unroll
          for (int ni = 0; ni < 4; ni++) Pw[ni * 16] = f2bf(v[ni]);
        }
#pragma unroll
        for (int nb = 0; nb < 8; nb++)
#pragma unroll
          for (int r = 0; r < 4; r++) o[mi][nb][r] *= alpha[r];
      }
      asm volatile("s_waitcnt lgkmcnt(0)" ::: "memory");  // Ps is wave-private

      // O += P V
      bf16x8 pa[2][2];
#pragma unroll
      for (int mi = 0; mi < 2; mi++)
#pragma unroll
        for (int kc2 = 0; kc2 < 2; kc2++)
          pa[mi][kc2] =
              *(const bf16x8*)&Ps[wave][(mi * 16 + l16) * 72 + kc2 * 32 + quad * 8];
#pragma unroll
      for (int nb = 0; nb < 8; nb++) {
        const int d = nb * 16 + l16;
#pragma unroll
        for (int kc2 = 0; kc2 < 2; kc2++) {
          const int chunk = kc2 * 4 + quad;
          bf16x8 bv = *(const bf16x8*)&Vt[d * 72 + ((chunk + (d >> 3)) & 7) * 8];
#pragma unroll
          for (int mi = 0; mi < 2; mi++)
            o[mi][nb] = __builtin_amdgcn_mfma_f32_16x16x32_bf16(pa[mi][kc2], bv,
                                                                o[mi][nb], 0, 0, 0);
        }
      }
    }

    // epilogue: out[b][h][row][d] = o / l
#pragma unroll
    for (int mi = 0; mi < 2; mi++) {
      unsigned short* Op =
          out + (size_t)((b * HH + h) * SS + q0w + mi * 16 + quad * 4) * HD + l16;
#pragma unroll
      for (int nb = 0; nb < 8; nb++)
#pragma unroll
        for (int r = 0; r < 4; r++)
          Op[(size_t)r * HD + nb * 16] = f2bf(o[mi][nb][r] / l_r[mi][r]);
    }
  }
}

// ---------------- launch ----------------
extern "C" void kernel_launch(void* const* d_in, const int* in_sizes, int n_in,
                              void* d_out, int out_size, void* d_ws, size_t ws_size,
                              hipStream_t stream) {
  const float* x = (const float*)d_in[0];
  const float* rms_w = (const float*)d_in[1];
  const float* w_qkv = (const float*)d_in[2];
  const float* w_out = (const float*)d_in[3];
  const float* w1 = (const float*)d_in[4];
  const float* b1 = (const float*)d_in[5];
  const float* w3 = (const float*)d_in[6];
  const float* b3 = (const float*)d_in[7];
  const float* w2 = (const float*)d_in[8];
  const float* b2 = (const float*)d_in[9];
  float* out = (float*)d_out;

  char* ws = (char*)d_ws;
  size_t off = 0;
  auto alloc = [&](size_t bytes) {
    char* p = ws + off;
    off += (bytes + 255) & ~(size_t)255;
    return p;
  };
  const int M = BB * SS;  // 4096
  unsigned short* wqkv_b = (unsigned short*)alloc((size_t)QKVD * DD * 2);
  unsigned short* wout_b = (unsigned short*)alloc((size_t)DD * DD * 2);
  unsigned short* w1_b = (unsigned short*)alloc((size_t)FF * DD * 2);
  unsigned short* w3_b = (unsigned short*)alloc((size_t)FF * DD * 2);
  unsigned short* w2_b = (unsigned short*)alloc((size_t)DD * FF * 2);
  unsigned short* xn_b = (unsigned short*)alloc((size_t)M * DD * 2);
  unsigned short* qkv_b = (unsigned short*)alloc((size_t)M * QKVD * 2);
  unsigned short* attn_b = (unsigned short*)alloc((size_t)M * DD * 2);
  unsigned short* h_b = (unsigned short*)alloc((size_t)M * DD * 2);
  unsigned short* act_b = (unsigned short*)alloc((size_t)M * FF * 2);
  // split-K fp32 partials (2 x M*DD*4 = 64 MB) alias xn_b..qkv_b (16+48 MB),
  // which are dead by the time w_out (and later w2) runs.
  float* part = (float*)xn_b;

  // weight converts
  f32_to_bf16_vec<<<(QKVD * DD / 4) / 256, 256, 0, stream>>>(w_qkv, wqkv_b, QKVD * DD / 4);
  f32_to_bf16_vec<<<(DD * DD / 4) / 256, 256, 0, stream>>>(w_out, wout_b, DD * DD / 4);
  f32_to_bf16_vec<<<(FF * DD / 4) / 256, 256, 0, stream>>>(w1, w1_b, FF * DD / 4);
  f32_to_bf16_vec<<<(FF * DD / 4) / 256, 256, 0, stream>>>(w3, w3_b, FF * DD / 4);
  f32_to_bf16_vec<<<(DD * FF / 4) / 256, 256, 0, stream>>>(w2, w2_b, DD * FF / 4);

  // rmsnorm
  rmsnorm_bf16<<<M, 256, 0, stream>>>(x, rms_w, xn_b);

  // qkv = xn @ w_qkv^T   (24x16 = 384 blocks)
  gemm_bt<0><<<dim3(QKVD / 256, M / 256), 512, 0, stream>>>(
      xn_b, wqkv_b, qkv_b, nullptr, nullptr, nullptr, M, QKVD, DD, DD);

  // attention (static balanced schedule, 256 blocks)
  attn_fwd<<<dim3(8, HH, BB), 256, 0, stream>>>(qkv_b, attn_b);

  // h = attn @ w_out^T   split-K=2: (8x16x2 = 256 blocks), then reduce
  gemm_bt<4><<<dim3(DD / 256, M / 256, 2), 512, 0, stream>>>(
      attn_b, wout_b, part, nullptr, nullptr, nullptr, M, DD, DD / 2, DD);
  reduce_wout<<<(M * DD / 4) / 256, 256, 0, stream>>>(part, h_b, M * DD / 4);

  // act = h @ w1^T + b1   (32x16 = 512 blocks)
  gemm_bt<1><<<dim3(FF / 256, M / 256), 512, 0, stream>>>(
      h_b, w1_b, act_b, b1, nullptr, nullptr, M, FF, DD, DD);

  // act = act + relu(h @ w3^T + b3)   (in-place aux read)
  gemm_bt<2><<<dim3(FF / 256, M / 256), 512, 0, stream>>>(
      h_b, w3_b, act_b, b3, act_b, nullptr, M, FF, DD, DD);

  // out = act @ w2^T + b2 + x   split-K=2: (8x16x2 = 256 blocks), then reduce
  gemm_bt<4><<<dim3(DD / 256, M / 256, 2), 512, 0, stream>>>(
      act_b, w2_b, part, nullptr, nullptr, nullptr, M, DD, FF / 2, FF);
  reduce_w2<<<(M * DD / 4) / 256, 256, 0, stream>>>(part, b2, x, out, M * DD / 4);
}

// Round 4
// 1141.354 us; speedup vs baseline: 1.3693x; 1.0421x over previous
//
#include <hip/hip_runtime.h>
#include <hip/hip_bf16.h>
#include <cstdint>

// Problem constants
#define BB 2
#define SS 2048
#define DD 2048
#define HH 16
#define HD 128
#define FF 8192
#define QKVD 6144  // 3*DD

typedef __bf16 bf16x8 __attribute__((ext_vector_type(8)));
typedef __bf16 bf16x4 __attribute__((ext_vector_type(4)));
typedef float floatx4 __attribute__((ext_vector_type(4)));

#define LOG2E 1.4426950408889634f

__device__ __forceinline__ unsigned short f2bf(float f) {
  unsigned u = __builtin_bit_cast(unsigned, f);
  u += 0x7FFFu + ((u >> 16) & 1u);
  return (unsigned short)(u >> 16);
}
__device__ __forceinline__ float bf2f(unsigned short h) {
  return __builtin_bit_cast(float, (unsigned)h << 16);
}

__device__ __forceinline__ void load_lds_16B(const void* g, void* l) {
  __builtin_amdgcn_global_load_lds(
      (const __attribute__((address_space(1))) unsigned int*)g,
      (__attribute__((address_space(3))) unsigned int*)l, 16, 0, 0);
}

// ---------------- fp32 -> bf16 convert ----------------
__global__ void f32_to_bf16_vec(const float* __restrict__ src,
                                unsigned short* __restrict__ dst, int n4) {
  int i = blockIdx.x * 256 + threadIdx.x;
  if (i < n4) {
    float4 v = ((const float4*)src)[i];
    ushort4 o;
    o.x = f2bf(v.x); o.y = f2bf(v.y); o.z = f2bf(v.z); o.w = f2bf(v.w);
    ((ushort4*)dst)[i] = o;
  }
}

// ---------------- RMSNorm (fp32 in, bf16 out) ----------------
__global__ __launch_bounds__(256) void rmsnorm_bf16(const float* __restrict__ x,
                                                    const float* __restrict__ w,
                                                    unsigned short* __restrict__ xn) {
  const int row = blockIdx.x, tid = threadIdx.x;
  const float4* xr = (const float4*)(x + (size_t)row * DD);
  float4 a = xr[tid], b = xr[tid + 256];
  float ss = a.x * a.x + a.y * a.y + a.z * a.z + a.w * a.w +
             b.x * b.x + b.y * b.y + b.z * b.z + b.w * b.w;
#pragma unroll
  for (int off = 1; off < 64; off <<= 1) ss += __shfl_xor(ss, off);
  __shared__ float red[4];
  if ((tid & 63) == 0) red[tid >> 6] = ss;
  __syncthreads();
  float tot = red[0] + red[1] + red[2] + red[3];
  float sc = rsqrtf(tot * (1.0f / (float)DD) + 1e-5f);
  const float4* wr = (const float4*)w;
  float4 wa = wr[tid], wb = wr[tid + 256];
  ushort4 oa, ob;
  oa.x = f2bf(a.x * sc * wa.x); oa.y = f2bf(a.y * sc * wa.y);
  oa.z = f2bf(a.z * sc * wa.z); oa.w = f2bf(a.w * sc * wa.w);
  ob.x = f2bf(b.x * sc * wb.x); ob.y = f2bf(b.y * sc * wb.y);
  ob.z = f2bf(b.z * sc * wb.z); ob.w = f2bf(b.w * sc * wb.w);
  *(ushort4*)&xn[(size_t)row * DD + tid * 4] = oa;
  *(ushort4*)&xn[(size_t)row * DD + (tid + 256) * 4] = ob;
}

// ---------------- split-K reduce kernels ----------------
// h_b = bf16(p0 + p1)
__global__ __launch_bounds__(256) void reduce_wout(const float* __restrict__ p,
                                                   unsigned short* __restrict__ outb,
                                                   int n4) {
  int i = blockIdx.x * 256 + threadIdx.x;
  if (i < n4) {
    float4 a = ((const float4*)p)[i];
    float4 b = ((const float4*)(p + (size_t)BB * SS * DD))[i];
    ushort4 o;
    o.x = f2bf(a.x + b.x); o.y = f2bf(a.y + b.y);
    o.z = f2bf(a.z + b.z); o.w = f2bf(a.w + b.w);
    ((ushort4*)outb)[i] = o;
  }
}

// out = p0 + p1 + b2[col] + x   (fp32)
__global__ __launch_bounds__(256) void reduce_w2(const float* __restrict__ p,
                                                 const float* __restrict__ b2,
                                                 const float* __restrict__ x,
                                                 float* __restrict__ out, int n4) {
  int i = blockIdx.x * 256 + threadIdx.x;
  if (i < n4) {
    float4 a = ((const float4*)p)[i];
    float4 b = ((const float4*)(p + (size_t)BB * SS * DD))[i];
    float4 xx = ((const float4*)x)[i];
    float4 bb = ((const float4*)b2)[i & (DD / 4 - 1)];
    float4 o;
    o.x = a.x + b.x + bb.x + xx.x;
    o.y = a.y + b.y + bb.y + xx.y;
    o.z = a.z + b.z + bb.z + xx.z;
    o.w = a.w + b.w + bb.w + xx.w;
    ((float4*)out)[i] = o;
  }
}

// ---------------- GEMM: C[M,N] = A[M,K] @ Bw[N,K]^T  (bf16 in, fp32 acc) ----
// 256x256 tile, BK=64, 8 waves (2M x 4N), 8-phase schedule with counted vmcnt.
// (unchanged from round 1/2 — measured 0 bank conflicts)
// MODE 0: bf16; 1: bf16(acc+bias); 2: bf16(aux+relu(acc+bias)); 3: fp32
// (acc+bias+res); 4: raw fp32 partial at z*M*N (split-K).
template <int MODE>
__global__ __launch_bounds__(512, 1) void gemm_bt(
    const unsigned short* __restrict__ A, const unsigned short* __restrict__ Bw,
    void* __restrict__ Cout, const float* __restrict__ bias,
    const unsigned short* __restrict__ aux, const float* __restrict__ res,
    int M, int N, int K, int lda) {
  __shared__ __align__(16) unsigned short As[2][2][128 * 64];
  __shared__ __align__(16) unsigned short Bs[2][2][128 * 64];
  const int tid = threadIdx.x;
  const int lane = tid & 63, w = tid >> 6;
  const int l16 = lane & 15, quad = lane >> 4;
  const int wm = w >> 2, wn = w & 3;

  const int gx = gridDim.x;
  const int nwg = gx * gridDim.y;
  const int bid = blockIdx.y * gx + blockIdx.x;
  const int cpx = nwg >> 3;
  const int swzb = (bid & 7) * cpx + (bid >> 3);
  const int n0 = (swzb % gx) * 256, m0 = (swzb / gx) * 256;
  const size_t koff = (size_t)blockIdx.z * K;

  const int NT = K >> 6, NIT = NT >> 1;

  const int sr = lane >> 3, sc = lane & 7;
  const unsigned short* pA0 =
      A + (size_t)(m0 + w * 8 + sr) * lda + koff + (sc ^ sr) * 8;
  const unsigned short* pA1 = pA0 + (size_t)128 * lda;
  const unsigned short* pB0 =
      Bw + (size_t)(n0 + (w >> 2) * 64 + (w & 3) * 8 + sr) * lda + koff + (sc ^ sr) * 8;
  const unsigned short* pB1 = pB0 + (size_t)128 * lda;

#define STAGE_A(d, h, kt)                                              \
  {                                                                    \
    const int _k = ((kt) < NT ? (kt) : NT - 1) * 64;                   \
    const size_t _ho = (size_t)(h) * 64 * lda;                         \
    load_lds_16B(pA0 + _ho + _k, &As[d][h][(w * 8) * 64]);             \
    load_lds_16B(pA1 + _ho + _k, &As[d][h][(64 + w * 8) * 64]);        \
  }
#define STAGE_B(d, h, kt)                                              \
  {                                                                    \
    const int _k = ((kt) < NT ? (kt) : NT - 1) * 64;                   \
    const size_t _ho = (size_t)(h) * 32 * lda;                         \
    load_lds_16B(pB0 + _ho + _k, &Bs[d][h][(w * 8) * 64]);             \
    load_lds_16B(pB1 + _ho + _k, &Bs[d][h][(64 + w * 8) * 64]);        \
  }

  floatx4 acc[2][2][4][2];
#pragma unroll
  for (int a0 = 0; a0 < 2; a0++)
#pragma unroll
    for (int a1 = 0; a1 < 2; a1++)
#pragma unroll
      for (int a2 = 0; a2 < 4; a2++)
#pragma unroll
        for (int a3 = 0; a3 < 2; a3++) acc[a0][a1][a2][a3] = floatx4{0.f, 0.f, 0.f, 0.f};
  bf16x8 bb[2][2];

#define PHASE(d, mq, nq, LOADB, STAGES, VMW)                                    \
  {                                                                             \
    bf16x8 a_[4][2];                                                            \
    _Pragma("unroll") for (int fr = 0; fr < 4; ++fr) {                          \
      const int lr_ = wm * 64 + fr * 16 + l16;                                  \
      _Pragma("unroll") for (int kc = 0; kc < 2; ++kc)                          \
        a_[fr][kc] = *(const bf16x8*)&As[d][mq]                                 \
            [lr_ * 64 + (((kc * 4 + quad) ^ (l16 & 7)) * 8)];                   \
    }                                                                           \
    if (LOADB) {                                                                \
      _Pragma("unroll") for (int fn = 0; fn < 2; ++fn) {                        \
        const int lr_ = wn * 32 + fn * 16 + l16;                                \
        _Pragma("unroll") for (int kc = 0; kc < 2; ++kc)                        \
          bb[fn][kc] = *(const bf16x8*)&Bs[d][nq]                               \
              [lr_ * 64 + (((kc * 4 + quad) ^ (l16 & 7)) * 8)];                 \
      }                                                                         \
    }                                                                           \
    STAGES                                                                      \
    __builtin_amdgcn_s_barrier();                                               \
    asm volatile("s_waitcnt lgkmcnt(0)" ::: "memory");                          \
    __builtin_amdgcn_sched_barrier(0);                                          \
    __builtin_amdgcn_s_setprio(1);                                              \
    _Pragma("unroll") for (int kc = 0; kc < 2; ++kc)                            \
      _Pragma("unroll") for (int fr = 0; fr < 4; ++fr)                          \
        _Pragma("unroll") for (int fn = 0; fn < 2; ++fn)                        \
          acc[mq][nq][fr][fn] = __builtin_amdgcn_mfma_f32_16x16x32_bf16(        \
              a_[fr][kc], bb[fn][kc], acc[mq][nq][fr][fn], 0, 0, 0);            \
    __builtin_amdgcn_s_setprio(0);                                              \
    if (VMW) asm volatile("s_waitcnt vmcnt(4)" ::: "memory");                   \
    __builtin_amdgcn_s_barrier();                                               \
    asm volatile("" ::: "memory");                                              \
  }

  STAGE_A(0, 0, 0)
  STAGE_A(0, 1, 0)
  STAGE_B(0, 0, 0)
  STAGE_B(0, 1, 0)
  STAGE_B(1, 0, 1)
  STAGE_A(1, 0, 1)
  asm volatile("s_waitcnt vmcnt(4)" ::: "memory");
  __builtin_amdgcn_s_barrier();
  asm volatile("" ::: "memory");

#pragma unroll 1
  for (int it = 0; it < NIT; ++it) {
    const int t1 = 2 * it + 1, tn0 = 2 * it + 2, tn1 = 2 * it + 3;
    PHASE(0, 0, 0, true,  STAGE_A(1, 1, t1) STAGE_B(1, 1, t1), false)
    PHASE(0, 1, 0, false, , false)
    PHASE(0, 0, 1, true,  STAGE_B(0, 0, tn0), false)
    PHASE(0, 1, 1, false, STAGE_A(0, 0, tn0), true)
    PHASE(1, 0, 0, true,  STAGE_A(0, 1, tn0) STAGE_B(0, 1, tn0), false)
    PHASE(1, 1, 0, false, , false)
    PHASE(1, 0, 1, true,  STAGE_B(1, 0, tn1), false)
    PHASE(1, 1, 1, false, STAGE_A(1, 0, tn1), true)
  }
  asm volatile("s_waitcnt vmcnt(0)" ::: "memory");
#undef PHASE
#undef STAGE_A
#undef STAGE_B

#pragma unroll
  for (int nq = 0; nq < 2; ++nq)
#pragma unroll
    for (int fn = 0; fn < 2; ++fn) {
      const int col = n0 + wn * 64 + nq * 32 + fn * 16 + l16;
      float bv = 0.0f;
      if constexpr (MODE >= 1 && MODE <= 3) bv = bias[col];
#pragma unroll
      for (int mq = 0; mq < 2; ++mq)
#pragma unroll
        for (int fr = 0; fr < 4; ++fr) {
          const int row0 = m0 + wm * 128 + mq * 64 + fr * 16 + quad * 4;
#pragma unroll
          for (int r = 0; r < 4; ++r) {
            const size_t idx = (size_t)(row0 + r) * N + col;
            float v = acc[mq][nq][fr][fn][r];
            if constexpr (MODE == 0) {
              ((unsigned short*)Cout)[idx] = f2bf(v);
            } else if constexpr (MODE == 1) {
              ((unsigned short*)Cout)[idx] = f2bf(v + bv);
            } else if constexpr (MODE == 2) {
              float t = fmaxf(v + bv, 0.0f) + bf2f(aux[idx]);
              ((unsigned short*)Cout)[idx] = f2bf(t);
            } else if constexpr (MODE == 3) {
              ((float*)Cout)[idx] = v + bv + res[idx];
            } else {
              ((float*)Cout)[(size_t)blockIdx.z * ((size_t)M * N) + idx] = v;
            }
          }
        }
    }
}

// ---------------- Flash causal attention v4 ----------------
// Grid (16, H, B) = 512 blocks, 2 blocks/CU (LDS = 80 KB exactly).
// Block (x,h,b) handles q-tile qt = (b==0 ? x : 15-x): under round-robin
// dispatch, co-resident blocks f and f+256 share (x,h) with complementary b,
// so per-CU work sums to a constant 34 KV-tile-iters.
// Pipeline per KV tile: loads for t+1 issued a full tile early (T14);
// K in LDS with GEMM-style XOR chunk swizzle; V row-major subtiled
// [kv/4][d/16][4][16] written with ds_write_b128 and consumed with
// ds_read_b64_tr_b16 (T10); P through wave-private XOR-swizzled LDS.
__global__ __launch_bounds__(256, 2) void attn_fwd(const unsigned short* __restrict__ qkv,
                                                   unsigned short* __restrict__ out) {
  __shared__ __align__(16) unsigned short Ks[2][64 * 128];
  __shared__ __align__(16) unsigned short Vs[2][64 * 128];
  __shared__ __align__(16) unsigned short Ps[4][32 * 64];
  const int tid = threadIdx.x;
  const int lane = tid & 63, wave = tid >> 6;
  const int l16 = lane & 15, quad = lane >> 4;
  const int h = blockIdx.y, b = blockIdx.z;
  const int qt = (b == 0) ? (int)blockIdx.x : 15 - (int)blockIdx.x;
  const float scale = 0.088388347648318447f;  // 1/sqrt(128)
  const int q0w = qt * 128 + wave * 32;
  const int ntiles = 2 * qt + 2;
  const int cc = tid & 15, rr = tid >> 4;
  // LDS byte offset of Vs[0] (computed once; tr-read addresses are vbase0 +
  // cur*16384 + per-lane offset).
  const unsigned vbase0 = (unsigned)(size_t)(
      __attribute__((address_space(3))) unsigned short*)&Vs[0][0];

  // Q fragments: 32 rows x 128 cols, held in registers
  bf16x8 aq[2][4];
#pragma unroll
  for (int mi = 0; mi < 2; mi++) {
    const unsigned short* Qp =
        qkv + (size_t)(b * SS + q0w + mi * 16 + l16) * QKVD + h * HD + quad * 8;
#pragma unroll
    for (int kc = 0; kc < 4; kc++) aq[mi][kc] = *(const bf16x8*)(Qp + kc * 32);
  }

  floatx4 o[2][8];
  float m_r[2][4], l_r[2][4];
#pragma unroll
  for (int mi = 0; mi < 2; mi++) {
#pragma unroll
    for (int nb = 0; nb < 8; nb++) o[mi][nb] = floatx4{0.f, 0.f, 0.f, 0.f};
#pragma unroll
    for (int r = 0; r < 4; r++) { m_r[mi][r] = -1e30f; l_r[mi][r] = 0.f; }
  }

  uint4 kreg[4], vreg[4];
  const unsigned short* kb = qkv + (size_t)b * SS * QKVD + h * HD + cc * 8 + DD;

#define AT_ISSUE(t)                                                           \
  _Pragma("unroll") for (int i = 0; i < 4; i++) {                             \
    const size_t rowb = (size_t)((t) * 64 + rr + 16 * i) * QKVD;              \
    kreg[i] = *(const uint4*)(kb + rowb);                                     \
    vreg[i] = *(const uint4*)(kb + rowb + DD);                                \
  }
#define AT_WRITE(dbuf)                                                        \
  _Pragma("unroll") for (int i = 0; i < 4; i++) {                             \
    const int r = rr + 16 * i;                                                \
    *(uint4*)&Ks[dbuf][r * 128 + ((cc & 8) | ((cc ^ r) & 7)) * 8] = kreg[i];  \
    *(uint4*)&Vs[dbuf][((r >> 2) * 8 + (cc >> 1)) * 64 + (r & 3) * 16 +       \
                       (cc & 1) * 8] = vreg[i];                               \
  }
// tr-read: 4 reads per (nb): kc2=0 lo/hi at +0/+1024, kc2=1 at +8192/+9216
#define AT_TRV(o0, o1, o2, o3, addr)                                          \
  asm volatile("ds_read_b64_tr_b16 %0, %4\n\t"                                \
               "ds_read_b64_tr_b16 %1, %4 offset:1024\n\t"                    \
               "ds_read_b64_tr_b16 %2, %4 offset:8192\n\t"                    \
               "ds_read_b64_tr_b16 %3, %4 offset:9216"                        \
               : "=&v"(o0), "=&v"(o1), "=&v"(o2), "=&v"(o3)                   \
               : "v"(addr) : "memory");
#define AT_MMA(s0, s1, s2, s3, nb, WN)                                        \
  asm volatile("s_waitcnt lgkmcnt(" WN ")" ::: "memory");                     \
  __builtin_amdgcn_sched_barrier(0);                                          \
  {                                                                           \
    bf16x8 bv0, bv1;                                                          \
    _Pragma("unroll") for (int j = 0; j < 4; j++) {                           \
      bv0[j] = s0[j]; bv0[4 + j] = s1[j];                                     \
      bv1[j] = s2[j]; bv1[4 + j] = s3[j];                                     \
    }                                                                         \
    o[0][nb] = __builtin_amdgcn_mfma_f32_16x16x32_bf16(pa[0][0], bv0,         \
                                                       o[0][nb], 0, 0, 0);    \
    o[1][nb] = __builtin_amdgcn_mfma_f32_16x16x32_bf16(pa[1][0], bv0,         \
                                                       o[1][nb], 0, 0, 0);    \
    o[0][nb] = __builtin_amdgcn_mfma_f32_16x16x32_bf16(pa[0][1], bv1,         \
                                                       o[0][nb], 0, 0, 0);    \
    o[1][nb] = __builtin_amdgcn_mfma_f32_16x16x32_bf16(pa[1][1], bv1,         \
                                                       o[1][nb], 0, 0, 0);    \
  }

  // prologue: tile0 -> buf0; issue tile1 loads
  AT_ISSUE(0)
  AT_WRITE(0)
  AT_ISSUE(1)
  __syncthreads();

#pragma unroll 1
  for (int t = 0; t < ntiles; t++) {
    const int cur = t & 1;
    const int kv0 = t * 64;
    const bool need_mask = (t >= ntiles - 2);

    // S = Q K^T  (32q x 64kv)
    floatx4 s[2][4];
#pragma unroll
    for (int mi = 0; mi < 2; mi++)
#pragma unroll
      for (int ni = 0; ni < 4; ni++) s[mi][ni] = floatx4{0.f, 0.f, 0.f, 0.f};
#pragma unroll
    for (int kc = 0; kc < 4; kc++) {
      bf16x8 bk[4];
#pragma unroll
      for (int ni = 0; ni < 4; ni++) {
        const int row = ni * 16 + l16;
        const int c = kc * 4 + quad;
        bk[ni] = *(const bf16x8*)&Ks[cur][row * 128 +
                                          ((c & 8) | ((c ^ row) & 7)) * 8];
      }
#pragma unroll
      for (int mi = 0; mi < 2; mi++)
#pragma unroll
        for (int ni = 0; ni < 4; ni++)
          s[mi][ni] = __builtin_amdgcn_mfma_f32_16x16x32_bf16(aq[mi][kc], bk[ni],
                                                              s[mi][ni], 0, 0, 0);
    }

    // online softmax
#pragma unroll
    for (int mi = 0; mi < 2; mi++) {
      float alpha[4];
#pragma unroll
      for (int r = 0; r < 4; r++) {
        const int qrow = q0w + mi * 16 + quad * 4 + r;
        float v[4];
#pragma unroll
        for (int ni = 0; ni < 4; ni++) {
          v[ni] = s[mi][ni][r] * scale;
          if (need_mask && (kv0 + ni * 16 + l16 > qrow)) v[ni] = -1e30f;
        }
        float mx = fmaxf(fmaxf(v[0], v[1]), fmaxf(v[2], v[3]));
        mx = fmaxf(mx, __shfl_xor(mx, 1));
        mx = fmaxf(mx, __shfl_xor(mx, 2));
        mx = fmaxf(mx, __shfl_xor(mx, 4));
        mx = fmaxf(mx, __shfl_xor(mx, 8));
        const float mnew = fmaxf(m_r[mi][r], mx);
        alpha[r] = exp2f((m_r[mi][r] - mnew) * LOG2E);
        m_r[mi][r] = mnew;
        float rs = 0.f;
#pragma unroll
        for (int ni = 0; ni < 4; ni++) {
          v[ni] = exp2f((v[ni] - mnew) * LOG2E);
          rs += v[ni];
        }
        rs += __shfl_xor(rs, 1);
        rs += __shfl_xor(rs, 2);
        rs += __shfl_xor(rs, 4);
        rs += __shfl_xor(rs, 8);
        l_r[mi][r] = l_r[mi][r] * alpha[r] + rs;
        const int prow = mi * 16 + quad * 4 + r;
        unsigned short* Pw = &Ps[wave][prow * 64 + (l16 & 7)];
        const int px = (prow & 7) * 8;
#pragma unroll
        for (int ni = 0; ni < 4; ni++)
          Pw[((ni * 2 + (l16 >> 3)) * 8) ^ px] = f2bf(v[ni]);
      }
#pragma unroll
      for (int nb = 0; nb < 8; nb++)
#pragma unroll
        for (int r = 0; r < 4; r++) o[mi][nb][r] *= alpha[r];
    }
    asm volatile("s_waitcnt lgkmcnt(0)" ::: "memory");  // Ps wave-private drain

    bf16x8 pa[2][2];
#pragma unroll
    for (int mi = 0; mi < 2; mi++)
#pragma unroll
      for (int kc2 = 0; kc2 < 2; kc2++)
        pa[mi][kc2] = *(const bf16x8*)&Ps[wave][(mi * 16 + l16) * 64 +
                                                (((kc2 * 4 + quad) ^ (l16 & 7)) * 8)];
    asm volatile("s_waitcnt lgkmcnt(0)" ::: "memory");
    __builtin_amdgcn_sched_barrier(0);

    // O += P V  via hardware transpose reads, 2-deep pipeline
    const unsigned va = vbase0 + (unsigned)cur * 16384u + quad * 2048 + l16 * 8;
    bf16x4 tA0, tA1, tA2, tA3, tB0, tB1, tB2, tB3;
    AT_TRV(tA0, tA1, tA2, tA3, va)
    AT_TRV(tB0, tB1, tB2, tB3, va + 128)
    AT_MMA(tA0, tA1, tA2, tA3, 0, "4")
    AT_TRV(tA0, tA1, tA2, tA3, va + 256)
    AT_MMA(tB0, tB1, tB2, tB3, 1, "4")
    AT_TRV(tB0, tB1, tB2, tB3, va + 384)
    AT_MMA(tA0, tA1, tA2, tA3, 2, "4")
    AT_TRV(tA0, tA1, tA2, tA3, va + 512)
    AT_MMA(tB0, tB1, tB2, tB3, 3, "4")
    AT_TRV(tB0, tB1, tB2, tB3, va + 640)
    AT_MMA(tA0, tA1, tA2, tA3, 4, "4")
    AT_TRV(tA0, tA1, tA2, tA3, va + 768)
    AT_MMA(tB0, tB1, tB2, tB3, 5, "4")
    AT_TRV(tB0, tB1, tB2, tB3, va + 896)
    AT_MMA(tA0, tA1, tA2, tA3, 6, "4")
    AT_MMA(tB0, tB1, tB2, tB3, 7, "0")

    // stage tile t+1 into the other buffer; issue loads for t+2
    if (t + 1 < ntiles) {
      __syncthreads();
      AT_WRITE(cur ^ 1)
      if (t + 2 < ntiles) AT_ISSUE(t + 2)
      __syncthreads();
    }
  }
#undef AT_ISSUE
#undef AT_WRITE
#undef AT_TRV
#undef AT_MMA

  // epilogue: out[b][h][row][d] = o / l
#pragma unroll
  for (int mi = 0; mi < 2; mi++) {
    unsigned short* Op =
        out + (size_t)((b * HH + h) * SS + q0w + mi * 16 + quad * 4) * HD + l16;
#pragma unroll
    for (int nb = 0; nb < 8; nb++)
#pragma unroll
      for (int r = 0; r < 4; r++)
        Op[(size_t)r * HD + nb * 16] = f2bf(o[mi][nb][r] / l_r[mi][r]);
  }
}

// ---------------- launch ----------------
extern "C" void kernel_launch(void* const* d_in, const int* in_sizes, int n_in,
                              void* d_out, int out_size, void* d_ws, size_t ws_size,
                              hipStream_t stream) {
  const float* x = (const float*)d_in[0];
  const float* rms_w = (const float*)d_in[1];
  const float* w_qkv = (const float*)d_in[2];
  const float* w_out = (const float*)d_in[3];
  const float* w1 = (const float*)d_in[4];
  const float* b1 = (const float*)d_in[5];
  const float* w3 = (const float*)d_in[6];
  const float* b3 = (const float*)d_in[7];
  const float* w2 = (const float*)d_in[8];
  const float* b2 = (const float*)d_in[9];
  float* out = (float*)d_out;

  char* ws = (char*)d_ws;
  size_t off = 0;
  auto alloc = [&](size_t bytes) {
    char* p = ws + off;
    off += (bytes + 255) & ~(size_t)255;
    return p;
  };
  const int M = BB * SS;  // 4096
  unsigned short* wqkv_b = (unsigned short*)alloc((size_t)QKVD * DD * 2);
  unsigned short* wout_b = (unsigned short*)alloc((size_t)DD * DD * 2);
  unsigned short* w1_b = (unsigned short*)alloc((size_t)FF * DD * 2);
  unsigned short* w3_b = (unsigned short*)alloc((size_t)FF * DD * 2);
  unsigned short* w2_b = (unsigned short*)alloc((size_t)DD * FF * 2);
  unsigned short* xn_b = (unsigned short*)alloc((size_t)M * DD * 2);
  unsigned short* qkv_b = (unsigned short*)alloc((size_t)M * QKVD * 2);
  unsigned short* attn_b = (unsigned short*)alloc((size_t)M * DD * 2);
  unsigned short* h_b = (unsigned short*)alloc((size_t)M * DD * 2);
  unsigned short* act_b = (unsigned short*)alloc((size_t)M * FF * 2);
  // split-K fp32 partials (2 x M*DD*4 = 64 MB) alias xn_b..qkv_b (16+48 MB),
  // which are dead by the time w_out (and later w2) runs.
  float* part = (float*)xn_b;

  // weight converts
  f32_to_bf16_vec<<<(QKVD * DD / 4) / 256, 256, 0, stream>>>(w_qkv, wqkv_b, QKVD * DD / 4);
  f32_to_bf16_vec<<<(DD * DD / 4) / 256, 256, 0, stream>>>(w_out, wout_b, DD * DD / 4);
  f32_to_bf16_vec<<<(FF * DD / 4) / 256, 256, 0, stream>>>(w1, w1_b, FF * DD / 4);
  f32_to_bf16_vec<<<(FF * DD / 4) / 256, 256, 0, stream>>>(w3, w3_b, FF * DD / 4);
  f32_to_bf16_vec<<<(DD * FF / 4) / 256, 256, 0, stream>>>(w2, w2_b, DD * FF / 4);

  // rmsnorm
  rmsnorm_bf16<<<M, 256, 0, stream>>>(x, rms_w, xn_b);

  // qkv = xn @ w_qkv^T   (24x16 = 384 blocks)
  gemm_bt<0><<<dim3(QKVD / 256, M / 256), 512, 0, stream>>>(
      xn_b, wqkv_b, qkv_b, nullptr, nullptr, nullptr, M, QKVD, DD, DD);

  // attention (512 blocks, 2/CU, complementary pairing)
  attn_fwd<<<dim3(16, HH, BB), 256, 0, stream>>>(qkv_b, attn_b);

  // h = attn @ w_out^T   split-K=2: (8x16x2 = 256 blocks), then reduce
  gemm_bt<4><<<dim3(DD / 256, M / 256, 2), 512, 0, stream>>>(
      attn_b, wout_b, part, nullptr, nullptr, nullptr, M, DD, DD / 2, DD);
  reduce_wout<<<(M * DD / 4) / 256, 256, 0, stream>>>(part, h_b, M * DD / 4);

  // act = h @ w1^T + b1   (32x16 = 512 blocks)
  gemm_bt<1><<<dim3(FF / 256, M / 256), 512, 0, stream>>>(
      h_b, w1_b, act_b, b1, nullptr, nullptr, M, FF, DD, DD);

  // act = act + relu(h @ w3^T + b3)   (in-place aux read)
  gemm_bt<2><<<dim3(FF / 256, M / 256), 512, 0, stream>>>(
      h_b, w3_b, act_b, b3, act_b, nullptr, M, FF, DD, DD);

  // out = act @ w2^T + b2 + x   split-K=2: (8x16x2 = 256 blocks), then reduce
  gemm_bt<4><<<dim3(DD / 256, M / 256, 2), 512, 0, stream>>>(
      act_b, w2_b, part, nullptr, nullptr, nullptr, M, DD, FF / 2, FF);
  reduce_w2<<<(M * DD / 4) / 256, 256, 0, stream>>>(part, b2, x, out, M * DD / 4);
}